// Round 1
// baseline (1099.689 us; speedup 1.0000x reference)
//
#include <hip/hip_runtime.h>
#include <math.h>

// ---------------------------------------------------------------------------
// Problem constants
// ---------------------------------------------------------------------------
#define BATCH 2048
#define NRIS  100
#define MN    16
#define DIN   303
#define DOUT  264   // 200 + 4*16
// THRESH_W = 1e-15  -> CCC = quad * 1e15f

// ---------------------------------------------------------------------------
// Generic fp32 GEMM:  C[M,N] = act(A[M,K] @ W[K,N] + bias[N])
// 64x64 block tile, 256 threads, 4x4 micro-tile per thread, K-tile = 16.
// M assumed multiple of 64; N,K arbitrary (guarded).
// ---------------------------------------------------------------------------
template <bool RELU>
__global__ __launch_bounds__(256) void gemm_kernel(
    const float* __restrict__ A, const float* __restrict__ W,
    const float* __restrict__ bias, float* __restrict__ C,
    int M, int N, int K)
{
    // +4 padding keeps float4 LDS reads 16B-aligned and bank conflicts <= 2-way (free)
    __shared__ __align__(16) float As[16][68];   // [k][m]
    __shared__ __align__(16) float Bs[16][68];   // [k][n]

    const int tid = threadIdx.x;
    const int tx  = tid & 15;   // micro col group
    const int ty  = tid >> 4;   // micro row group
    const int bm  = blockIdx.x * 64;
    const int bn  = blockIdx.y * 64;

    const int la_k = tid & 15;  // A loader: k within tile
    const int la_m = tid >> 4;  // A loader: row base (+p*16)
    const int lb_n = tid & 63;  // B loader: col (coalesced)
    const int lb_k = tid >> 6;  // B loader: k base (+p*4)

    float acc[4][4];
#pragma unroll
    for (int i = 0; i < 4; ++i)
#pragma unroll
        for (int j = 0; j < 4; ++j) acc[i][j] = 0.f;

    for (int k0 = 0; k0 < K; k0 += 16) {
        // stage A tile (64 rows x 16 k), transposed into As[k][m]
#pragma unroll
        for (int p = 0; p < 4; ++p) {
            int m  = la_m + p * 16;
            int gk = k0 + la_k;
            float v = 0.f;
            if (gk < K) v = A[(size_t)(bm + m) * K + gk];
            As[la_k][m] = v;
        }
        // stage B tile (16 k x 64 n), coalesced along n
#pragma unroll
        for (int p = 0; p < 4; ++p) {
            int k  = lb_k + p * 4;
            int gk = k0 + k;
            int gn = bn + lb_n;
            float v = 0.f;
            if (gk < K && gn < N) v = W[(size_t)gk * N + gn];
            Bs[k][lb_n] = v;
        }
        __syncthreads();

#pragma unroll
        for (int kk = 0; kk < 16; ++kk) {
            float4 a4 = *(const float4*)&As[kk][ty * 4];
            float4 b4 = *(const float4*)&Bs[kk][tx * 4];
            float a_[4] = {a4.x, a4.y, a4.z, a4.w};
            float b_[4] = {b4.x, b4.y, b4.z, b4.w};
#pragma unroll
            for (int i = 0; i < 4; ++i)
#pragma unroll
                for (int j = 0; j < 4; ++j)
                    acc[i][j] = fmaf(a_[i], b_[j], acc[i][j]);
        }
        __syncthreads();
    }

    // epilogue: bias + optional relu
    if (bn + 64 <= N) {
        float4 bb = *(const float4*)&bias[bn + tx * 4];
#pragma unroll
        for (int i = 0; i < 4; ++i) {
            int gm = bm + ty * 4 + i;
            float4 v;
            v.x = acc[i][0] + bb.x;
            v.y = acc[i][1] + bb.y;
            v.z = acc[i][2] + bb.z;
            v.w = acc[i][3] + bb.w;
            if (RELU) {
                v.x = fmaxf(v.x, 0.f); v.y = fmaxf(v.y, 0.f);
                v.z = fmaxf(v.z, 0.f); v.w = fmaxf(v.w, 0.f);
            }
            *(float4*)&C[(size_t)gm * N + bn + tx * 4] = v;
        }
    } else {
#pragma unroll
        for (int i = 0; i < 4; ++i) {
            int gm = bm + ty * 4 + i;
#pragma unroll
            for (int j = 0; j < 4; ++j) {
                int gn = bn + tx * 4 + j;
                if (gn < N) {
                    float v = acc[i][j] + bias[gn];
                    if (RELU) v = fmaxf(v, 0.f);
                    C[(size_t)gm * N + gn] = v;
                }
            }
        }
    }
}

// ---------------------------------------------------------------------------
// theta_prep: per sample
//   - unit-modulus theta -> thU[b][0:100]=Re, [100:200]=Im
//   - F1/F2 sqrt(2/||F||^2) normalization -> out[b][200:264]
// ---------------------------------------------------------------------------
__global__ __launch_bounds__(128) void theta_prep_kernel(
    const float* __restrict__ th1, float* __restrict__ thU,
    float* __restrict__ out)
{
    int b   = blockIdx.x;
    int tid = threadIdx.x;  // 128 threads
    const float* row = th1 + (size_t)b * DOUT;
    __shared__ float sc[2];

    if (tid == 112) {
        float s = 0.f;
        for (int j = 0; j < MN; ++j) {
            float fr = row[200 + j], fi = row[200 + MN + j];
            s += fr * fr + fi * fi;
        }
        sc[0] = sqrtf(2.f / s);
    } else if (tid == 113) {
        float s = 0.f;
        for (int j = 0; j < MN; ++j) {
            float fr = row[200 + 2 * MN + j], fi = row[200 + 3 * MN + j];
            s += fr * fr + fi * fi;
        }
        sc[1] = sqrtf(2.f / s);
    }

    if (tid < NRIS) {
        float re = row[tid], im = row[NRIS + tid];
        float r  = sqrtf(re * re + im * im);
        thU[(size_t)b * 200 + tid]        = re / r;
        thU[(size_t)b * 200 + NRIS + tid] = im / r;
    }
    __syncthreads();
    if (tid < 32) {
        int j = tid & 15, h = tid >> 4;  // h=0: real, h=1: imag
        out[(size_t)b * DOUT + 200 + h * MN + j]          = row[200 + h * MN + j] * sc[0];
        out[(size_t)b * DOUT + 200 + 2 * MN + h * MN + j] = row[200 + 2 * MN + h * MN + j] * sc[1];
    }
}

// ---------------------------------------------------------------------------
// quad: one block per (b,c). quad[bc] = Re(theta^H T theta)
//     = sum_{n,m} R(a_n a_m + b_n b_m) + I(b_n a_m - a_n b_m)
// Streams T_real/T_imag with float4 loads (memory-bound: 655 MB total).
// ---------------------------------------------------------------------------
__global__ __launch_bounds__(256) void quad_kernel(
    const float* __restrict__ Tr, const float* __restrict__ Ti,
    const float* __restrict__ thU, float* __restrict__ quad)
{
    int bc = blockIdx.x;        // b*4 + c
    int b  = bc >> 2;
    int tid = threadIdx.x;

    __shared__ __align__(16) float sA[NRIS];
    __shared__ __align__(16) float sB[NRIS];
    if (tid < 200) {
        float v = thU[(size_t)b * 200 + tid];
        if (tid < NRIS) sA[tid] = v;
        else            sB[tid - NRIS] = v;
    }
    __syncthreads();

    const float4* R4 = (const float4*)(Tr + (size_t)bc * (NRIS * NRIS));
    const float4* I4 = (const float4*)(Ti + (size_t)bc * (NRIS * NRIS));

    float acc = 0.f;
    // 10000 floats = 2500 float4 chunks; each chunk stays within one row (100%4==0)
    for (int j = tid; j < 2500; j += 256) {
        int n  = j / 25;
        int mb = (j - n * 25) * 4;
        float4 r  = R4[j];
        float4 im = I4[j];
        float an = sA[n], bn = sB[n];
        float4 am = *(const float4*)&sA[mb];
        float4 bm = *(const float4*)&sB[mb];
        acc += r.x * (an * am.x + bn * bm.x) + im.x * (bn * am.x - an * bm.x);
        acc += r.y * (an * am.y + bn * bm.y) + im.y * (bn * am.y - an * bm.y);
        acc += r.z * (an * am.z + bn * bm.z) + im.z * (bn * am.z - an * bm.z);
        acc += r.w * (an * am.w + bn * bm.w) + im.w * (bn * am.w - an * bm.w);
    }

    // wave reduce (64-wide) then cross-wave via LDS
    for (int off = 32; off > 0; off >>= 1) acc += __shfl_down(acc, off, 64);
    __shared__ float wsum[4];
    int wave = tid >> 6, lane = tid & 63;
    if (lane == 0) wsum[wave] = acc;
    __syncthreads();
    if (tid == 0) quad[bc] = wsum[0] + wsum[1] + wsum[2] + wsum[3];
}

// ---------------------------------------------------------------------------
// finalize: scale = 1/sqrt(max(max_c(quad*1e15), 1)); out[b][0:200] = thU*scale
// ---------------------------------------------------------------------------
__global__ __launch_bounds__(128) void finalize_kernel(
    const float* __restrict__ thU, const float* __restrict__ quad,
    float* __restrict__ out)
{
    int b   = blockIdx.x;
    int tid = threadIdx.x;
    __shared__ float sc;
    if (tid == 0) {
        const float* q = quad + (size_t)b * 4;
        float mx = fmaxf(fmaxf(q[0], q[1]), fmaxf(q[2], q[3])) * 1e15f;
        sc = 1.f / sqrtf(fmaxf(mx, 1.0f));
    }
    __syncthreads();
    if (tid < NRIS) {
        out[(size_t)b * DOUT + tid]        = thU[(size_t)b * 200 + tid] * sc;
        out[(size_t)b * DOUT + NRIS + tid] = thU[(size_t)b * 200 + NRIS + tid] * sc;
    }
}

// ---------------------------------------------------------------------------
// launch
// ---------------------------------------------------------------------------
extern "C" void kernel_launch(void* const* d_in, const int* in_sizes, int n_in,
                              void* d_out, int out_size, void* d_ws, size_t ws_size,
                              hipStream_t stream)
{
    const float* sample1 = (const float*)d_in[0];
    const float* T_real  = (const float*)d_in[1];
    const float* T_imag  = (const float*)d_in[2];
    const float* W1 = (const float*)d_in[3];
    const float* b1 = (const float*)d_in[4];
    const float* W2 = (const float*)d_in[5];
    const float* b2 = (const float*)d_in[6];
    const float* W3 = (const float*)d_in[7];
    const float* b3 = (const float*)d_in[8];
    const float* W4 = (const float*)d_in[9];
    const float* b4 = (const float*)d_in[10];
    float* out = (float*)d_out;

    // workspace layout (floats); h3 reuses h1's region (h1 dead after GEMM2)
    float* ws   = (float*)d_ws;
    float* h1   = ws;                                   // 2048*1024
    float* h2   = ws + (size_t)BATCH * 1024;            // 2048*1024
    float* h3   = ws;                                   // 2048*512 (reuse)
    float* th1  = ws + (size_t)2 * BATCH * 1024;        // 2048*264
    float* thU  = th1 + (size_t)BATCH * DOUT;           // 2048*200
    float* quad = thU + (size_t)BATCH * 200;            // 2048*4

    dim3 blk(256);
    gemm_kernel<true><<<dim3(BATCH / 64, 1024 / 64), blk, 0, stream>>>(
        sample1, W1, b1, h1, BATCH, 1024, DIN);
    gemm_kernel<true><<<dim3(BATCH / 64, 1024 / 64), blk, 0, stream>>>(
        h1, W2, b2, h2, BATCH, 1024, 1024);
    gemm_kernel<true><<<dim3(BATCH / 64, 512 / 64), blk, 0, stream>>>(
        h2, W3, b3, h3, BATCH, 512, 1024);
    gemm_kernel<false><<<dim3(BATCH / 64, (DOUT + 63) / 64), blk, 0, stream>>>(
        h3, W4, b4, th1, BATCH, DOUT, 512);

    theta_prep_kernel<<<dim3(BATCH), dim3(128), 0, stream>>>(th1, thU, out);
    quad_kernel<<<dim3(BATCH * 4), dim3(256), 0, stream>>>(T_real, T_imag, thU, quad);
    finalize_kernel<<<dim3(BATCH), dim3(128), 0, stream>>>(thU, quad, out);
}

// Round 2
// 971.509 us; speedup vs baseline: 1.1319x; 1.1319x over previous
//
#include <hip/hip_runtime.h>
#include <math.h>

// ---------------------------------------------------------------------------
// Problem constants
// ---------------------------------------------------------------------------
#define BATCH 2048
#define NRIS  100
#define MN    16
#define DIN   303
#define DOUT  264   // 200 + 4*16
// THRESH_W = 1e-15  -> CCC = quad * 1e15f

// ---------------------------------------------------------------------------
// async 16B global->LDS DMA (wave-uniform LDS base + lane*16 semantics)
// ---------------------------------------------------------------------------
__device__ __forceinline__ void gload_lds16(const float* g, float* lds) {
    __builtin_amdgcn_global_load_lds(
        (const __attribute__((address_space(1))) unsigned int*)g,
        (__attribute__((address_space(3))) unsigned int*)lds, 16, 0, 0);
}

// ---------------------------------------------------------------------------
// Pipelined fp32 GEMM: C[M,N] = act(A[M,K] @ W[K,N] + bias[N])
// BM=128, BK=16, 256 threads, micro-tile 8xTN, BN = 16*TN (TN=8 or 4).
// Double-buffered LDS; A staged via registers, B via global_load_lds DMA.
// Requires: M%128==0, N%BN==0, bm/bn full tiles (no N/M guards).
// K arbitrary (A zero-fills OOB k; B clamps address, A-zero kills product).
// VECA: A rows 16B-aligned & K%4==0 -> float4 A staging.
// ---------------------------------------------------------------------------
template <int BN, int TN, bool RELU, bool VECA>
__global__ __launch_bounds__(256) void gemm_pipe(
    const float* __restrict__ A, const float* __restrict__ W,
    const float* __restrict__ bias, float* __restrict__ C,
    int M, int N, int K)
{
    __shared__ __align__(16) float As[2][16][132];  // [buf][k][m], pad 132: 2-way only
    __shared__ __align__(16) float Bs[2][16][BN];   // [buf][k][n], DMA target (contiguous)

    const int tid = threadIdx.x;
    const int tx  = tid & 15;    // col group
    const int ty  = tid >> 4;    // row group (0..15)
    const int w   = tid >> 6;    // wave id (uniform per wave)
    const int l   = tid & 63;
    const int bm  = blockIdx.x * 128;
    const int bn  = blockIdx.y * BN;

    const int nt = (K + 15) / 16;

    // ---- A staging state ----
    float areg[8];
    // scalar path mapping
    const int la_k = tid & 15;
    const int la_m = tid >> 4;
    // vector path mapping: f4 index f in [0,512): r=f>>2, q=f&3
    const int va_r0 = tid >> 2;        // rows 0..63
    const int va_q  = tid & 3;

    auto loadA = [&](int k0) {
        if (VECA) {
            const float4* p0 = (const float4*)(A + (size_t)(bm + va_r0) * K + k0 + 4 * va_q);
            const float4* p1 = (const float4*)(A + (size_t)(bm + 64 + va_r0) * K + k0 + 4 * va_q);
            float4 v0 = *p0, v1 = *p1;
            areg[0] = v0.x; areg[1] = v0.y; areg[2] = v0.z; areg[3] = v0.w;
            areg[4] = v1.x; areg[5] = v1.y; areg[6] = v1.z; areg[7] = v1.w;
        } else {
            int gk = k0 + la_k;
            bool ok = gk < K;
#pragma unroll
            for (int p = 0; p < 8; ++p) {
                int m = la_m + 16 * p;
                areg[p] = ok ? A[(size_t)(bm + m) * K + gk] : 0.f;
            }
        }
    };
    auto writeA = [&](int buf) {
        if (VECA) {
#pragma unroll
            for (int j = 0; j < 4; ++j) {
                As[buf][4 * va_q + j][va_r0]      = areg[j];
                As[buf][4 * va_q + j][64 + va_r0] = areg[4 + j];
            }
        } else {
#pragma unroll
            for (int p = 0; p < 8; ++p)
                As[buf][la_k][la_m + 16 * p] = areg[p];
        }
    };
    auto issueB = [&](int k0, int buf) {
        // tile = 16 x BN floats = 4*BN float4s; one DMA inst covers 64 f4s/wave
#pragma unroll
        for (int c = 0; c < (4 * BN) / 256; ++c) {
            int gbase = c * 256 + w * 64;          // wave-uniform f4 base
            int g  = gbase + l;
            int k  = g / (BN / 4);
            int n4 = g % (BN / 4);
            int gk = k0 + k; if (gk > K - 1) gk = K - 1;   // clamp; A=0 kills it
            gload_lds16(W + (size_t)gk * N + bn + 4 * n4,
                        &Bs[buf][0][0] + (size_t)gbase * 4);
        }
    };

    float acc[8][TN];
#pragma unroll
    for (int i = 0; i < 8; ++i)
#pragma unroll
        for (int j = 0; j < TN; ++j) acc[i][j] = 0.f;

    // ---- prologue: tile 0 -> buf 0 ----
    loadA(0);
    issueB(0, 0);
    writeA(0);
    __syncthreads();

    for (int t = 0; t < nt; ++t) {
        int cur = t & 1, nxt = cur ^ 1;
        if (t + 1 < nt) {
            loadA((t + 1) * 16);
            issueB((t + 1) * 16, nxt);
        }
        // compute on buf[cur]
#pragma unroll
        for (int kk = 0; kk < 16; ++kk) {
            const float* as = &As[cur][kk][0];
            const float* bs = &Bs[cur][kk][0];
            float4 a0 = *(const float4*)(as + ty * 4);
            float4 a1 = *(const float4*)(as + 64 + ty * 4);
            float a_[8] = {a0.x, a0.y, a0.z, a0.w, a1.x, a1.y, a1.z, a1.w};
            float b_[TN];
            float4 b0 = *(const float4*)(bs + tx * 4);
            b_[0] = b0.x; b_[1] = b0.y; b_[2] = b0.z; b_[3] = b0.w;
            if (TN == 8) {
                float4 b1 = *(const float4*)(bs + 64 + tx * 4);
                b_[4] = b1.x; b_[5] = b1.y; b_[6] = b1.z; b_[7] = b1.w;
            }
#pragma unroll
            for (int i = 0; i < 8; ++i)
#pragma unroll
                for (int j = 0; j < TN; ++j)
                    acc[i][j] = fmaf(a_[i], b_[j], acc[i][j]);
        }
        if (t + 1 < nt) writeA(nxt);
        __syncthreads();
    }

    // ---- epilogue ----
    float4 bb0 = *(const float4*)&bias[bn + tx * 4];
    float4 bb1;
    if (TN == 8) bb1 = *(const float4*)&bias[bn + 64 + tx * 4];
    float bbs[8] = {bb0.x, bb0.y, bb0.z, bb0.w,
                    (TN == 8) ? bb1.x : 0.f, (TN == 8) ? bb1.y : 0.f,
                    (TN == 8) ? bb1.z : 0.f, (TN == 8) ? bb1.w : 0.f};
#pragma unroll
    for (int h = 0; h < 2; ++h) {
#pragma unroll
        for (int i = 0; i < 4; ++i) {
            int gm = bm + h * 64 + ty * 4 + i;
            int ri = h * 4 + i;
            float4 v;
            v.x = acc[ri][0] + bbs[0]; v.y = acc[ri][1] + bbs[1];
            v.z = acc[ri][2] + bbs[2]; v.w = acc[ri][3] + bbs[3];
            if (RELU) {
                v.x = fmaxf(v.x, 0.f); v.y = fmaxf(v.y, 0.f);
                v.z = fmaxf(v.z, 0.f); v.w = fmaxf(v.w, 0.f);
            }
            *(float4*)&C[(size_t)gm * N + bn + tx * 4] = v;
            if (TN == 8) {
                float4 u;
                u.x = acc[ri][4] + bbs[4]; u.y = acc[ri][5] + bbs[5];
                u.z = acc[ri][6] + bbs[6]; u.w = acc[ri][7] + bbs[7];
                if (RELU) {
                    u.x = fmaxf(u.x, 0.f); u.y = fmaxf(u.y, 0.f);
                    u.z = fmaxf(u.z, 0.f); u.w = fmaxf(u.w, 0.f);
                }
                *(float4*)&C[(size_t)gm * N + bn + 64 + tx * 4] = u;
            }
        }
    }
}

// ---------------------------------------------------------------------------
// Legacy 64x64 GEMM (used only for GEMM4: N=264 ragged, 0.55 GFLOP)
// ---------------------------------------------------------------------------
template <bool RELU>
__global__ __launch_bounds__(256) void gemm_kernel(
    const float* __restrict__ A, const float* __restrict__ W,
    const float* __restrict__ bias, float* __restrict__ C,
    int M, int N, int K)
{
    __shared__ __align__(16) float As[16][68];
    __shared__ __align__(16) float Bs[16][68];

    const int tid = threadIdx.x;
    const int tx  = tid & 15;
    const int ty  = tid >> 4;
    const int bm  = blockIdx.x * 64;
    const int bn  = blockIdx.y * 64;

    const int la_k = tid & 15;
    const int la_m = tid >> 4;
    const int lb_n = tid & 63;
    const int lb_k = tid >> 6;

    float acc[4][4];
#pragma unroll
    for (int i = 0; i < 4; ++i)
#pragma unroll
        for (int j = 0; j < 4; ++j) acc[i][j] = 0.f;

    for (int k0 = 0; k0 < K; k0 += 16) {
#pragma unroll
        for (int p = 0; p < 4; ++p) {
            int m  = la_m + p * 16;
            int gk = k0 + la_k;
            float v = 0.f;
            if (gk < K) v = A[(size_t)(bm + m) * K + gk];
            As[la_k][m] = v;
        }
#pragma unroll
        for (int p = 0; p < 4; ++p) {
            int k  = lb_k + p * 4;
            int gk = k0 + k;
            int gn = bn + lb_n;
            float v = 0.f;
            if (gk < K && gn < N) v = W[(size_t)gk * N + gn];
            Bs[k][lb_n] = v;
        }
        __syncthreads();
#pragma unroll
        for (int kk = 0; kk < 16; ++kk) {
            float4 a4 = *(const float4*)&As[kk][ty * 4];
            float4 b4 = *(const float4*)&Bs[kk][tx * 4];
            float a_[4] = {a4.x, a4.y, a4.z, a4.w};
            float b_[4] = {b4.x, b4.y, b4.z, b4.w};
#pragma unroll
            for (int i = 0; i < 4; ++i)
#pragma unroll
                for (int j = 0; j < 4; ++j)
                    acc[i][j] = fmaf(a_[i], b_[j], acc[i][j]);
        }
        __syncthreads();
    }

    if (bn + 64 <= N) {
        float4 bb = *(const float4*)&bias[bn + tx * 4];
#pragma unroll
        for (int i = 0; i < 4; ++i) {
            int gm = bm + ty * 4 + i;
            float4 v;
            v.x = acc[i][0] + bb.x; v.y = acc[i][1] + bb.y;
            v.z = acc[i][2] + bb.z; v.w = acc[i][3] + bb.w;
            if (RELU) {
                v.x = fmaxf(v.x, 0.f); v.y = fmaxf(v.y, 0.f);
                v.z = fmaxf(v.z, 0.f); v.w = fmaxf(v.w, 0.f);
            }
            *(float4*)&C[(size_t)gm * N + bn + tx * 4] = v;
        }
    } else {
#pragma unroll
        for (int i = 0; i < 4; ++i) {
            int gm = bm + ty * 4 + i;
#pragma unroll
            for (int j = 0; j < 4; ++j) {
                int gn = bn + tx * 4 + j;
                if (gn < N) {
                    float v = acc[i][j] + bias[gn];
                    if (RELU) v = fmaxf(v, 0.f);
                    C[(size_t)gm * N + gn] = v;
                }
            }
        }
    }
}

// ---------------------------------------------------------------------------
// theta_prep: unit-modulus theta -> thU; F1/F2 normalization -> out[200:264]
// ---------------------------------------------------------------------------
__global__ __launch_bounds__(128) void theta_prep_kernel(
    const float* __restrict__ th1, float* __restrict__ thU,
    float* __restrict__ out)
{
    int b   = blockIdx.x;
    int tid = threadIdx.x;
    const float* row = th1 + (size_t)b * DOUT;
    __shared__ float sc[2];

    if (tid == 112) {
        float s = 0.f;
        for (int j = 0; j < MN; ++j) {
            float fr = row[200 + j], fi = row[200 + MN + j];
            s += fr * fr + fi * fi;
        }
        sc[0] = sqrtf(2.f / s);
    } else if (tid == 113) {
        float s = 0.f;
        for (int j = 0; j < MN; ++j) {
            float fr = row[200 + 2 * MN + j], fi = row[200 + 3 * MN + j];
            s += fr * fr + fi * fi;
        }
        sc[1] = sqrtf(2.f / s);
    }

    if (tid < NRIS) {
        float re = row[tid], im = row[NRIS + tid];
        float r  = sqrtf(re * re + im * im);
        thU[(size_t)b * 200 + tid]        = re / r;
        thU[(size_t)b * 200 + NRIS + tid] = im / r;
    }
    __syncthreads();
    if (tid < 32) {
        int j = tid & 15, h = tid >> 4;
        out[(size_t)b * DOUT + 200 + h * MN + j]          = row[200 + h * MN + j] * sc[0];
        out[(size_t)b * DOUT + 200 + 2 * MN + h * MN + j] = row[200 + 2 * MN + h * MN + j] * sc[1];
    }
}

// ---------------------------------------------------------------------------
// quad: one block per (b,c). quad[bc] = Re(theta^H T theta). 655 MB stream.
// ---------------------------------------------------------------------------
__global__ __launch_bounds__(256) void quad_kernel(
    const float* __restrict__ Tr, const float* __restrict__ Ti,
    const float* __restrict__ thU, float* __restrict__ quad)
{
    int bc = blockIdx.x;
    int b  = bc >> 2;
    int tid = threadIdx.x;

    __shared__ __align__(16) float sA[NRIS];
    __shared__ __align__(16) float sB[NRIS];
    if (tid < 200) {
        float v = thU[(size_t)b * 200 + tid];
        if (tid < NRIS) sA[tid] = v;
        else            sB[tid - NRIS] = v;
    }
    __syncthreads();

    const float4* R4 = (const float4*)(Tr + (size_t)bc * (NRIS * NRIS));
    const float4* I4 = (const float4*)(Ti + (size_t)bc * (NRIS * NRIS));

    float acc = 0.f;
    for (int j = tid; j < 2500; j += 256) {
        int n  = j / 25;
        int mb = (j - n * 25) * 4;
        float4 r  = R4[j];
        float4 im = I4[j];
        float an = sA[n], bn = sB[n];
        float4 am = *(const float4*)&sA[mb];
        float4 bm = *(const float4*)&sB[mb];
        acc += r.x * (an * am.x + bn * bm.x) + im.x * (bn * am.x - an * bm.x);
        acc += r.y * (an * am.y + bn * bm.y) + im.y * (bn * am.y - an * bm.y);
        acc += r.z * (an * am.z + bn * bm.z) + im.z * (bn * am.z - an * bm.z);
        acc += r.w * (an * am.w + bn * bm.w) + im.w * (bn * am.w - an * bm.w);
    }

    for (int off = 32; off > 0; off >>= 1) acc += __shfl_down(acc, off, 64);
    __shared__ float wsum[4];
    int wave = tid >> 6, lane = tid & 63;
    if (lane == 0) wsum[wave] = acc;
    __syncthreads();
    if (tid == 0) quad[bc] = wsum[0] + wsum[1] + wsum[2] + wsum[3];
}

// ---------------------------------------------------------------------------
// finalize: scale = rsqrt(max(max_c(quad*1e15), 1)); out[b][0:200] = thU*scale
// ---------------------------------------------------------------------------
__global__ __launch_bounds__(128) void finalize_kernel(
    const float* __restrict__ thU, const float* __restrict__ quad,
    float* __restrict__ out)
{
    int b   = blockIdx.x;
    int tid = threadIdx.x;
    __shared__ float sc;
    if (tid == 0) {
        const float* q = quad + (size_t)b * 4;
        float mx = fmaxf(fmaxf(q[0], q[1]), fmaxf(q[2], q[3])) * 1e15f;
        sc = 1.f / sqrtf(fmaxf(mx, 1.0f));
    }
    __syncthreads();
    if (tid < NRIS) {
        out[(size_t)b * DOUT + tid]        = thU[(size_t)b * 200 + tid] * sc;
        out[(size_t)b * DOUT + NRIS + tid] = thU[(size_t)b * 200 + NRIS + tid] * sc;
    }
}

// ---------------------------------------------------------------------------
// launch
// ---------------------------------------------------------------------------
extern "C" void kernel_launch(void* const* d_in, const int* in_sizes, int n_in,
                              void* d_out, int out_size, void* d_ws, size_t ws_size,
                              hipStream_t stream)
{
    const float* sample1 = (const float*)d_in[0];
    const float* T_real  = (const float*)d_in[1];
    const float* T_imag  = (const float*)d_in[2];
    const float* W1 = (const float*)d_in[3];
    const float* b1 = (const float*)d_in[4];
    const float* W2 = (const float*)d_in[5];
    const float* b2 = (const float*)d_in[6];
    const float* W3 = (const float*)d_in[7];
    const float* b3 = (const float*)d_in[8];
    const float* W4 = (const float*)d_in[9];
    const float* b4 = (const float*)d_in[10];
    float* out = (float*)d_out;

    float* ws   = (float*)d_ws;
    float* h1   = ws;                                   // 2048*1024
    float* h2   = ws + (size_t)BATCH * 1024;            // 2048*1024
    float* h3   = ws;                                   // 2048*512 (reuse h1)
    float* th1  = ws + (size_t)2 * BATCH * 1024;        // 2048*264
    float* thU  = th1 + (size_t)BATCH * DOUT;           // 2048*200
    float* quad = thU + (size_t)BATCH * 200;            // 2048*4

    dim3 blk(256);
    // GEMM1: 303 -> 1024 (K=303: scalar A staging)
    gemm_pipe<128, 8, true, false><<<dim3(BATCH / 128, 1024 / 128), blk, 0, stream>>>(
        sample1, W1, b1, h1, BATCH, 1024, DIN);
    // GEMM2: 1024 -> 1024
    gemm_pipe<128, 8, true, true><<<dim3(BATCH / 128, 1024 / 128), blk, 0, stream>>>(
        h1, W2, b2, h2, BATCH, 1024, 1024);
    // GEMM3: 1024 -> 512 (BN=64 for 128-block grid)
    gemm_pipe<64, 4, true, true><<<dim3(BATCH / 128, 512 / 64), blk, 0, stream>>>(
        h2, W3, b3, h3, BATCH, 512, 1024);
    // GEMM4: 512 -> 264 (ragged N, legacy kernel)
    gemm_kernel<false><<<dim3(BATCH / 64, (DOUT + 63) / 64), blk, 0, stream>>>(
        h3, W4, b4, th1, BATCH, DOUT, 512);

    theta_prep_kernel<<<dim3(BATCH), dim3(128), 0, stream>>>(th1, thU, out);
    quad_kernel<<<dim3(BATCH * 4), dim3(256), 0, stream>>>(T_real, T_imag, thU, quad);
    finalize_kernel<<<dim3(BATCH), dim3(128), 0, stream>>>(thU, quad, out);
}